// Round 3
// baseline (482.543 us; speedup 1.0000x reference)
//
#include <hip/hip_runtime.h>
#include <stdint.h>

typedef float f32x4 __attribute__((ext_vector_type(4)));
typedef float f32x2 __attribute__((ext_vector_type(2)));
typedef short bf16x8 __attribute__((ext_vector_type(8)));
typedef uint32_t u32x4 __attribute__((ext_vector_type(4)));

__device__ __forceinline__ uint32_t bf16_rne(float f) {
  uint32_t x = __float_as_uint(f);
  return (x + 0x7FFFu + ((x >> 16) & 1u)) >> 16;
}

// LDS-only barrier: waits this wave's DS ops, does NOT drain vmcnt ->
// W-prefetch global loads stay in flight across the barrier.
__device__ __forceinline__ void ldsbar() {
  asm volatile("s_waitcnt lgkmcnt(0)\n\ts_barrier" ::: "memory");
}

// ---------------- kernel 0: cast x (f32) -> bf16 ----------------
__global__ void cast_x_kernel(const float* __restrict__ x,
                              uint32_t* __restrict__ xb, int n2) {
  int i = blockIdx.x * 256 + threadIdx.x;
  if (i >= n2) return;
  f32x2 v = *(const f32x2*)(x + 2 * i);
  xb[i] = bf16_rne(v[0]) | (bf16_rne(v[1]) << 16);
}

// ---------------- fused per-class GEMM ----------------
// Block: M=256 (full batch) x N=64 of one class, BK=64, 8 waves (8M x 1N),
// per-wave tile 32x64, acc[2][4] = 32 VGPR.
// A: bf16, read DIRECTLY from global per-fragment (L2/L3-resident; 128 B
//    contiguous per row per K-step) -> no A LDS, no global_load_lds DMA.
// B: W f32, lane owns column n=l, wave owns k-octet w -> 8 coalesced dword
//    loads -> pack 8 bf16 -> one swizzled ds_write_b128, double-buffered.
// Barriers are LDS-only (lgkmcnt), so the W HBM stream never drains.
// MODE 0: epilogue bias+relu -> bf16 store.  MODE 1: bias+relu -> W3 dot ->
// shfl-reduce -> f32 partials (layer 3 fused, h2 never materialized).
template <int K, int MODE>
__global__ __launch_bounds__(512, 4) void gemm_fused(
    const uint16_t* __restrict__ Abase, long long aClassStride,
    const float* __restrict__ Wbase, const float* __restrict__ biasBase,
    uint16_t* __restrict__ Hout, const float* __restrict__ W3base,
    float* __restrict__ part) {
  constexpr int NT = K / 64;
  __shared__ uint8_t smem[16384];  // 2 x (B 8K)

  const int tid = threadIdx.x;
  const int bid = blockIdx.x;
  // bijective XCD swizzle (4096 % 8 == 0): class's 8 n-tiles on one XCD
  const int logical = ((bid & 7) << 9) | (bid >> 3);
  const int c = logical >> 3;
  const int nt = logical & 7;
  const int n0 = nt * 64;

  const uint16_t* Ab = Abase + (size_t)c * (size_t)aClassStride;
  const float* Wc = Wbase + (size_t)c * (K * 512) + n0;

  const int l = tid & 63, w = tid >> 6;
  const int lr = l & 15, lg = l >> 4;

  // lane's A base: row (w*32 + lr), k-octet lg
  const uint16_t* Ap = Ab + (size_t)(w * 32 + lr) * K + lg * 8;

  f32x4 acc[2][4];
#pragma unroll
  for (int i = 0; i < 2; i++)
#pragma unroll
    for (int j = 0; j < 4; j++) acc[i][j] = {0.f, 0.f, 0.f, 0.f};

  auto loadB = [&](int ts, float* g) {
    const float* Ws = Wc + (size_t)(ts * 64 + w * 8) * 512 + l;
#pragma unroll
    for (int r = 0; r < 8; r++) g[r] = Ws[(size_t)r * 512];
  };
  auto writeB = [&](const float* g, int buf) {
    u32x4 p;
#pragma unroll
    for (int j = 0; j < 4; j++)
      p[j] = bf16_rne(g[2 * j]) | (bf16_rne(g[2 * j + 1]) << 16);
    *(u32x4*)(smem + buf * 8192 + l * 128 + ((w ^ (l & 7)) << 4)) = p;
  };
  auto comp = [&](int buf, int t) {
    const uint8_t* s = smem + buf * 8192;
    bf16x8 a[4];  // [kk][mf] issued first so vmcnt waits leave W in flight
#pragma unroll
    for (int kk = 0; kk < 2; ++kk)
#pragma unroll
      for (int mf = 0; mf < 2; mf++)
        a[kk * 2 + mf] =
            *(const bf16x8*)(Ap + t * 64 + kk * 32 + (size_t)mf * 16 * K);
#pragma unroll
    for (int kk = 0; kk < 2; ++kk) {
      const int kx = ((lg * 16) ^ ((lr & 7) << 4)) ^ (kk << 6);
      bf16x8 b[4];
#pragma unroll
      for (int nf = 0; nf < 4; nf++)
        b[nf] = *(const bf16x8*)(s + (nf * 16 + lr) * 128 + kx);
#pragma unroll
      for (int mf = 0; mf < 2; mf++)
#pragma unroll
        for (int nf = 0; nf < 4; nf++)
          acc[mf][nf] = __builtin_amdgcn_mfma_f32_16x16x32_bf16(
              a[kk * 2 + mf], b[nf], acc[mf][nf], 0, 0, 0);
    }
  };

  float g0[8], g1[8];
  loadB(0, g0);
  loadB(1, g1);
  writeB(g0, 0);  // waits only g0's 8 loads (vmcnt(8)); g1 stays in flight
  ldsbar();

#pragma unroll 1
  for (int t = 0; t < NT; t += 2) {
    comp(0, t);
    if (t + 2 < NT) loadB(t + 2, g0);
    writeB(g1, 1);
    ldsbar();
    comp(1, t + 1);
    if (t + 3 < NT) loadB(t + 3, g1);
    if (t + 2 < NT) {
      writeB(g0, 0);
      ldsbar();
    }
  }

  float bv[4];
#pragma unroll
  for (int nf = 0; nf < 4; nf++)
    bv[nf] = biasBase[c * 512 + n0 + nf * 16 + lr];

  if constexpr (MODE == 0) {
    uint16_t* Oc = Hout + (size_t)c * 131072 + n0;
#pragma unroll
    for (int mf = 0; mf < 2; mf++)
#pragma unroll
      for (int nf = 0; nf < 4; nf++)
#pragma unroll
        for (int r = 0; r < 4; r++) {
          int m = w * 32 + mf * 16 + lg * 4 + r;
          float v = fmaxf(acc[mf][nf][r] + bv[nf], 0.f);
          Oc[(size_t)m * 512 + nf * 16 + lr] = (uint16_t)bf16_rne(v);
        }
  } else {
    float w30[4], w31[4];
#pragma unroll
    for (int nf = 0; nf < 4; nf++) {
      f32x2 t = *(const f32x2*)(W3base +
                                ((size_t)c * 512 + n0 + nf * 16 + lr) * 2);
      w30[nf] = t[0];
      w31[nf] = t[1];
    }
#pragma unroll
    for (int mf = 0; mf < 2; mf++)
#pragma unroll
      for (int r = 0; r < 4; r++) {
        float s0 = 0.f, s1 = 0.f;
#pragma unroll
        for (int nf = 0; nf < 4; nf++) {
          float v = fmaxf(acc[mf][nf][r] + bv[nf], 0.f);
          s0 += v * w30[nf];
          s1 += v * w31[nf];
        }
#pragma unroll
        for (int d = 1; d < 16; d <<= 1) {
          s0 += __shfl_xor(s0, d);
          s1 += __shfl_xor(s1, d);
        }
        if (lr == 0) {
          int m = w * 32 + mf * 16 + lg * 4 + r;
          *(f32x2*)(part + (((size_t)c * 256 + m) * 8 + nt) * 2) =
              f32x2{s0, s1};
        }
      }
  }
}

// ---------------- reduce partials -> out [B][C][2] ----------------
__global__ __launch_bounds__(512) void reduce_out(
    const float* __restrict__ part, const float* __restrict__ b3,
    float* __restrict__ out) {
  const int b = blockIdx.x, c = threadIdx.x;
  const f32x4* p = (const f32x4*)(part + ((size_t)c * 256 + b) * 16);
  f32x4 v0 = p[0], v1 = p[1], v2 = p[2], v3 = p[3];
  float s0 = b3[c * 2] + v0[0] + v0[2] + v1[0] + v1[2] + v2[0] + v2[2] +
             v3[0] + v3[2];
  float s1 = b3[c * 2 + 1] + v0[1] + v0[3] + v1[1] + v1[3] + v2[1] + v2[3] +
             v3[1] + v3[3];
  *(f32x2*)(out + ((size_t)b * 512 + c) * 2) = f32x2{s0, s1};
}

extern "C" void kernel_launch(void* const* d_in, const int* in_sizes, int n_in,
                              void* d_out, int out_size, void* d_ws,
                              size_t ws_size, hipStream_t stream) {
  const float* x = (const float*)d_in[0];
  const float* W1 = (const float*)d_in[1];
  const float* b1 = (const float*)d_in[2];
  const float* W2 = (const float*)d_in[3];
  const float* b2 = (const float*)d_in[4];
  const float* W3 = (const float*)d_in[5];
  const float* b3 = (const float*)d_in[6];
  float* out = (float*)d_out;

  uint8_t* ws = (uint8_t*)d_ws;
  const size_t xb_off = 0;
  const size_t h1_off = 393216;                // 256*768*2
  const size_t part_off = h1_off + 134217728;  // + 512*256*512*2
  const size_t need = part_off + 8388608;      // + 512*256*8*2*4
  if (ws_size < need) return;

  uint32_t* xb = (uint32_t*)(ws + xb_off);
  uint16_t* h1 = (uint16_t*)(ws + h1_off);
  float* part = (float*)(ws + part_off);

  cast_x_kernel<<<dim3(384), dim3(256), 0, stream>>>(x, xb, 98304);
  gemm_fused<768, 0><<<dim3(4096), dim3(512), 0, stream>>>(
      (const uint16_t*)xb, 0LL, W1, b1, h1, nullptr, nullptr);
  gemm_fused<512, 1><<<dim3(4096), dim3(512), 0, stream>>>(
      h1, 131072LL, W2, b2, nullptr, W3, part);
  reduce_out<<<dim3(256), dim3(512), 0, stream>>>(part, b3, out);
}

// Round 4
// 464.829 us; speedup vs baseline: 1.0381x; 1.0381x over previous
//
#include <hip/hip_runtime.h>
#include <stdint.h>

typedef float f32x4 __attribute__((ext_vector_type(4)));
typedef float f32x2 __attribute__((ext_vector_type(2)));
typedef short bf16x8 __attribute__((ext_vector_type(8)));
typedef uint32_t u32x4 __attribute__((ext_vector_type(4)));

__device__ __forceinline__ uint32_t bf16_rne(float f) {
  uint32_t x = __float_as_uint(f);
  return (x + 0x7FFFu + ((x >> 16) & 1u)) >> 16;
}

// LDS-only barrier: waits this wave's DS ops, does NOT drain vmcnt.
// Memory clobber also pins global-load issue placement (no sink/hoist).
__device__ __forceinline__ void ldsbar() {
  asm volatile("s_waitcnt lgkmcnt(0)\n\ts_barrier" ::: "memory");
}

// ---------------- kernel 0: cast x (f32) -> bf16 ----------------
__global__ void cast_x_kernel(const float* __restrict__ x,
                              uint32_t* __restrict__ xb, int n2) {
  int i = blockIdx.x * 256 + threadIdx.x;
  if (i >= n2) return;
  f32x2 v = *(const f32x2*)(x + 2 * i);
  xb[i] = bf16_rne(v[0]) | (bf16_rne(v[1]) << 16);
}

// ---------------- fused per-class GEMM ----------------
// Block: M=256 (full batch) x N=64 of one class, BK=64, 8 waves (8M x 1N).
// A: bf16, prefetched from global (L2/L3) into frag regs 2 phases early.
// B: W f32, prefetched 3 phases early into 3-set reg rotation -> bf16 pack ->
//    swizzled ds_write_b128 into 2-buffer LDS (only 16 KB LDS total).
// Barriers are lgkm-only; every vmcnt wait targets loads >= 2 phases old, so
// the HBM W-stream never drains (AITER-style counted-wait pipeline).
// MODE 0: bias+relu -> bf16 store.  MODE 1: bias+relu -> W3 dot -> shfl
// reduce -> f32 partials (layer 3 fused).
template <int K, int MODE>
__global__ __launch_bounds__(512, 4) void gemm_fused(
    const uint16_t* __restrict__ Abase, long long aClassStride,
    const float* __restrict__ Wbase, const float* __restrict__ biasBase,
    uint16_t* __restrict__ Hout, const float* __restrict__ W3base,
    float* __restrict__ part) {
  constexpr int NT = K / 64;
  __shared__ uint8_t smem[16384];  // 2 x (B 8K)

  const int tid = threadIdx.x;
  const int bid = blockIdx.x;
  // bijective XCD swizzle (4096 % 8 == 0): class's 8 n-tiles on one XCD
  const int logical = ((bid & 7) << 9) | (bid >> 3);
  const int c = logical >> 3;
  const int nt = logical & 7;
  const int n0 = nt * 64;

  const uint16_t* Ab = Abase + (size_t)c * (size_t)aClassStride;
  const float* Wc = Wbase + (size_t)c * (K * 512) + n0;

  const int l = tid & 63, w = tid >> 6;
  const int lr = l & 15, lg = l >> 4;

  // lane's A base: row (w*32 + lr), k-octet lg
  const uint16_t* Ap = Ab + (size_t)(w * 32 + lr) * K + lg * 8;

  f32x4 acc[2][4];
#pragma unroll
  for (int i = 0; i < 2; i++)
#pragma unroll
    for (int j = 0; j < 4; j++) acc[i][j] = {0.f, 0.f, 0.f, 0.f};

  auto loadB = [&](int ts, float* g) {
    const float* Ws = Wc + (size_t)(ts * 64 + w * 8) * 512 + l;
#pragma unroll
    for (int r = 0; r < 8; r++) g[r] = Ws[(size_t)r * 512];
  };
  auto loadA = [&](int ts, bf16x8* as) {
#pragma unroll
    for (int kk = 0; kk < 2; ++kk)
#pragma unroll
      for (int mf = 0; mf < 2; mf++)
        as[kk * 2 + mf] =
            *(const bf16x8*)(Ap + ts * 64 + kk * 32 + (size_t)mf * 16 * K);
  };
  auto writeB = [&](const float* g, int buf) {
    u32x4 p;
#pragma unroll
    for (int j = 0; j < 4; j++)
      p[j] = bf16_rne(g[2 * j]) | (bf16_rne(g[2 * j + 1]) << 16);
    *(u32x4*)(smem + buf * 8192 + l * 128 + ((w ^ (l & 7)) << 4)) = p;
  };
  auto comp = [&](int buf, const bf16x8* as) {
    const uint8_t* s = smem + buf * 8192;
#pragma unroll
    for (int kk = 0; kk < 2; ++kk) {
      const int kx = ((lg * 16) ^ ((lr & 7) << 4)) ^ (kk << 6);
      bf16x8 b[4];
#pragma unroll
      for (int nf = 0; nf < 4; nf++)
        b[nf] = *(const bf16x8*)(s + (nf * 16 + lr) * 128 + kx);
#pragma unroll
      for (int mf = 0; mf < 2; mf++)
#pragma unroll
        for (int nf = 0; nf < 4; nf++)
          acc[mf][nf] = __builtin_amdgcn_mfma_f32_16x16x32_bf16(
              as[kk * 2 + mf], b[nf], acc[mf][nf], 0, 0, 0);
    }
  };

  float g[3][8];
  bf16x8 a[2][4];
  loadB(0, g[0]);
  loadB(1, g[1]);
  loadA(0, a[0]);
  writeB(g[0], 0);  // waits only W(0); W(1)/A(0) stay in flight
  loadA(1, a[1]);
  loadB(2, g[2]);
  ldsbar();

#pragma unroll
  for (int t = 0; t < NT; ++t) {
    comp(t & 1, a[t & 1]);                      // waits A(t) (oldest)
    if (t + 1 < NT) writeB(g[(t + 1) % 3], (t + 1) & 1);  // waits W(t+1)
    if (t + 2 < NT) loadA(t + 2, a[t & 1]);     // issue 2 phases ahead
    if (t + 3 < NT) loadB(t + 3, g[t % 3]);     // issue 3 phases ahead
    if (t + 1 < NT) ldsbar();                   // publish buf (t+1)&1
  }

  float bv[4];
#pragma unroll
  for (int nf = 0; nf < 4; nf++)
    bv[nf] = biasBase[c * 512 + n0 + nf * 16 + lr];

  if constexpr (MODE == 0) {
    uint16_t* Oc = Hout + (size_t)c * 131072 + n0;
#pragma unroll
    for (int mf = 0; mf < 2; mf++)
#pragma unroll
      for (int nf = 0; nf < 4; nf++)
#pragma unroll
        for (int r = 0; r < 4; r++) {
          int m = w * 32 + mf * 16 + lg * 4 + r;
          float v = fmaxf(acc[mf][nf][r] + bv[nf], 0.f);
          Oc[(size_t)m * 512 + nf * 16 + lr] = (uint16_t)bf16_rne(v);
        }
  } else {
    float w30[4], w31[4];
#pragma unroll
    for (int nf = 0; nf < 4; nf++) {
      f32x2 t = *(const f32x2*)(W3base +
                                ((size_t)c * 512 + n0 + nf * 16 + lr) * 2);
      w30[nf] = t[0];
      w31[nf] = t[1];
    }
#pragma unroll
    for (int mf = 0; mf < 2; mf++)
#pragma unroll
      for (int r = 0; r < 4; r++) {
        float s0 = 0.f, s1 = 0.f;
#pragma unroll
        for (int nf = 0; nf < 4; nf++) {
          float v = fmaxf(acc[mf][nf][r] + bv[nf], 0.f);
          s0 += v * w30[nf];
          s1 += v * w31[nf];
        }
#pragma unroll
        for (int d = 1; d < 16; d <<= 1) {
          s0 += __shfl_xor(s0, d);
          s1 += __shfl_xor(s1, d);
        }
        if (lr == 0) {
          int m = w * 32 + mf * 16 + lg * 4 + r;
          *(f32x2*)(part + (((size_t)c * 256 + m) * 8 + nt) * 2) =
              f32x2{s0, s1};
        }
      }
  }
}

// ---------------- reduce partials -> out [B][C][2] ----------------
__global__ __launch_bounds__(512) void reduce_out(
    const float* __restrict__ part, const float* __restrict__ b3,
    float* __restrict__ out) {
  const int b = blockIdx.x, c = threadIdx.x;
  const f32x4* p = (const f32x4*)(part + ((size_t)c * 256 + b) * 16);
  f32x4 v0 = p[0], v1 = p[1], v2 = p[2], v3 = p[3];
  float s0 = b3[c * 2] + v0[0] + v0[2] + v1[0] + v1[2] + v2[0] + v2[2] +
             v3[0] + v3[2];
  float s1 = b3[c * 2 + 1] + v0[1] + v0[3] + v1[1] + v1[3] + v2[1] + v2[3] +
             v3[1] + v3[3];
  *(f32x2*)(out + ((size_t)b * 512 + c) * 2) = f32x2{s0, s1};
}

extern "C" void kernel_launch(void* const* d_in, const int* in_sizes, int n_in,
                              void* d_out, int out_size, void* d_ws,
                              size_t ws_size, hipStream_t stream) {
  const float* x = (const float*)d_in[0];
  const float* W1 = (const float*)d_in[1];
  const float* b1 = (const float*)d_in[2];
  const float* W2 = (const float*)d_in[3];
  const float* b2 = (const float*)d_in[4];
  const float* W3 = (const float*)d_in[5];
  const float* b3 = (const float*)d_in[6];
  float* out = (float*)d_out;

  uint8_t* ws = (uint8_t*)d_ws;
  const size_t xb_off = 0;
  const size_t h1_off = 393216;                // 256*768*2
  const size_t part_off = h1_off + 134217728;  // + 512*256*512*2
  const size_t need = part_off + 8388608;      // + 512*256*8*2*4
  if (ws_size < need) return;

  uint32_t* xb = (uint32_t*)(ws + xb_off);
  uint16_t* h1 = (uint16_t*)(ws + h1_off);
  float* part = (float*)(ws + part_off);

  cast_x_kernel<<<dim3(384), dim3(256), 0, stream>>>(x, xb, 98304);
  gemm_fused<768, 0><<<dim3(4096), dim3(512), 0, stream>>>(
      (const uint16_t*)xb, 0LL, W1, b1, h1, nullptr, nullptr);
  gemm_fused<512, 1><<<dim3(4096), dim3(512), 0, stream>>>(
      h1, 131072LL, W2, b2, nullptr, W3, part);
  reduce_out<<<dim3(256), dim3(512), 0, stream>>>(part, b3, out);
}

// Round 5
// 410.933 us; speedup vs baseline: 1.1743x; 1.1312x over previous
//
#include <hip/hip_runtime.h>
#include <stdint.h>

typedef float f32x4 __attribute__((ext_vector_type(4)));
typedef float f32x2 __attribute__((ext_vector_type(2)));
typedef short bf16x8 __attribute__((ext_vector_type(8)));
typedef uint32_t u32x4 __attribute__((ext_vector_type(4)));

__device__ __forceinline__ uint32_t bf16_rne(float f) {
  uint32_t x = __float_as_uint(f);
  return (x + 0x7FFFu + ((x >> 16) & 1u)) >> 16;
}

// LDS-only barrier: waits this wave's DS ops, does NOT drain vmcnt.
// Memory clobber pins global-load issue placement across phases.
__device__ __forceinline__ void ldsbar() {
  asm volatile("s_waitcnt lgkmcnt(0)\n\ts_barrier" ::: "memory");
}

// ---------------- kernel 0: cast x (f32) -> bf16 ----------------
__global__ void cast_x_kernel(const float* __restrict__ x,
                              uint32_t* __restrict__ xb, int n2) {
  int i = blockIdx.x * 256 + threadIdx.x;
  if (i >= n2) return;
  f32x2 v = *(const f32x2*)(x + 2 * i);
  xb[i] = bf16_rne(v[0]) | (bf16_rne(v[1]) << 16);
}

// ---------------- fully-fused 3-layer MLP, one class x half-batch ----------
// Block = (class c, mh half of 128 rows). 512 thr (8 waves, wave tile 16xN).
// L1: h1[128][512] bf16 computed n-tile by n-tile into LDS (128 KB region).
// L2: A-frags ds_read from h1-LDS; W2 streamed like W1.
// L3: fused per-n-tile W3 dot, accumulated in regs, stored at end.
// W stream: 4-deep reg rotation -> bf16 pack -> swizzled ds_write_b128,
// double-buffered; barriers lgkm-only; vmcnt stream strictly monotone.
// bias1/bias2/W3/b3 staged to LDS at start (epilogues do NO global loads).
// LDS map: 0 Bbuf0 | 8K Bbuf1 | 16K bias1 | 18K bias2 | 20K W3 | 24K b3
//          | 28K h1 (128K)  = 156 KB -> 1 block/CU.
__global__ __launch_bounds__(512, 2) void fused_mlp(
    const uint16_t* __restrict__ xb, const float* __restrict__ W1,
    const float* __restrict__ b1, const float* __restrict__ W2,
    const float* __restrict__ b2, const float* __restrict__ W3,
    const float* __restrict__ b3, float* __restrict__ out) {
  constexpr int H1OFF = 28672;
  __shared__ uint8_t smem[159744];

  const int tid = threadIdx.x;
  const int bid = blockIdx.x;
  // xcd = bid&7; pair (c, mh=0/1) = bids differing by 8 -> same XCD, concurrent
  const int logical = ((bid & 7) << 7) | (bid >> 3);
  const int c = logical >> 1;
  const int mh = logical & 1;

  const float* W1c = W1 + (size_t)c * (768 * 512);
  const float* W2c = W2 + (size_t)c * (512 * 512);

  const int l = tid & 63, w = tid >> 6;
  const int lr = l & 15, lg = l >> 4;

  // stage per-class small tensors into LDS (oldest loads in vmcnt stream)
  ((float*)(smem + 16384))[tid] = b1[(size_t)c * 512 + tid];
  ((float*)(smem + 18432))[tid] = b2[(size_t)c * 512 + tid];
  ((float*)(smem + 20480))[tid] = W3[(size_t)c * 1024 + tid];
  ((float*)(smem + 20480))[tid + 512] = W3[(size_t)c * 1024 + 512 + tid];
  if (tid < 2) ((float*)(smem + 24576))[tid] = b3[c * 2 + tid];

  const uint16_t* Ap1 = xb + (size_t)(mh * 128 + w * 16 + lr) * 768 + lg * 8;
  const int h1rd = H1OFF + (w * 16 + lr) * 1024;

  f32x4 acc[4];
#pragma unroll
  for (int j = 0; j < 4; j++) acc[j] = {0.f, 0.f, 0.f, 0.f};

  auto loadB = [&](const float* Wc, int nts, int ts, float* g) {
    const float* p = Wc + (size_t)(ts * 64 + w * 8) * 512 + nts * 64 + l;
#pragma unroll
    for (int r = 0; r < 8; r++) g[r] = p[(size_t)r * 512];
  };
  auto loadA1 = [&](int ts, bf16x8* a2) {
    a2[0] = *(const bf16x8*)(Ap1 + ts * 64);
    a2[1] = *(const bf16x8*)(Ap1 + ts * 64 + 32);
  };
  auto writeB = [&](const float* g, int buf) {
    u32x4 p;
#pragma unroll
    for (int j = 0; j < 4; j++)
      p[j] = bf16_rne(g[2 * j]) | (bf16_rne(g[2 * j + 1]) << 16);
    *(u32x4*)(smem + buf * 8192 + l * 128 + ((w ^ (l & 7)) << 4)) = p;
  };
  auto compB = [&](int buf, int kk) {
    const uint8_t* s = smem + buf * 8192;
    const int kx = ((lg * 16) ^ ((lr & 7) << 4)) ^ (kk << 6);
    bf16x8 b0 = *(const bf16x8*)(s + (0 * 16 + lr) * 128 + kx);
    bf16x8 b1f = *(const bf16x8*)(s + (1 * 16 + lr) * 128 + kx);
    bf16x8 b2f = *(const bf16x8*)(s + (2 * 16 + lr) * 128 + kx);
    bf16x8 b3f = *(const bf16x8*)(s + (3 * 16 + lr) * 128 + kx);
    struct { bf16x8 b[4]; } r = {{b0, b1f, b2f, b3f}};
    return r;
  };
  auto comp1 = [&](int buf, const bf16x8* a2) {
#pragma unroll
    for (int kk = 0; kk < 2; ++kk) {
      auto bb = compB(buf, kk);
#pragma unroll
      for (int nf = 0; nf < 4; nf++)
        acc[nf] = __builtin_amdgcn_mfma_f32_16x16x32_bf16(a2[kk], bb.b[nf],
                                                          acc[nf], 0, 0, 0);
    }
  };
  auto comp2 = [&](int buf, int ts) {
#pragma unroll
    for (int kk = 0; kk < 2; ++kk) {
      bf16x8 av = *(const bf16x8*)(
          smem + h1rd + ((ts * 8 + ((kk * 4 + lg) ^ (lr & 7))) << 4));
      auto bb = compB(buf, kk);
#pragma unroll
      for (int nf = 0; nf < 4; nf++)
        acc[nf] = __builtin_amdgcn_mfma_f32_16x16x32_bf16(av, bb.b[nf],
                                                          acc[nf], 0, 0, 0);
    }
  };

  float g[4][8];
  bf16x8 a[2][2];

  // ---------------- layer 1: 8 n-tiles x 12 K-steps ----------------
  loadB(W1c, 0, 0, g[0]);
  loadB(W1c, 0, 1, g[1]);
  loadA1(0, a[0]);
  loadB(W1c, 0, 2, g[2]);
  loadA1(1, a[1]);
  loadB(W1c, 0, 3, g[3]);
  writeB(g[0], 0);
  ldsbar();

#pragma unroll 1
  for (int so = 0; so < 8; ++so) {
#pragma unroll
    for (int k = 0; k < 12; ++k) {
      comp1(k & 1, a[k & 1]);
      if (k == 11) {  // epilogue: bias+relu -> h1 LDS (swizzled), acc reset
        const int n0 = so * 64;
#pragma unroll
        for (int nf = 0; nf < 4; nf++) {
          float bv = ((const float*)(smem + 16384))[n0 + nf * 16 + lr];
#pragma unroll
          for (int r = 0; r < 4; r++) {
            int row = w * 16 + lg * 4 + r;
            int ch = so * 8 + nf * 2 + (lr >> 3);
            float v = fmaxf(acc[nf][r] + bv, 0.f);
            *(uint16_t*)(smem + H1OFF + row * 1024 +
                         ((ch ^ (row & 7)) << 4) + (lr & 7) * 2) =
                (uint16_t)bf16_rne(v);
          }
          acc[nf] = {0.f, 0.f, 0.f, 0.f};
        }
      }
      const bool last = (so == 7 && k == 11);
      if (!last) writeB(g[(k + 1) & 3], (k + 1) & 1);
      if (!(so == 7 && k >= 10)) loadA1((k + 2) % 12, a[k & 1]);
      if (!(so == 7 && k >= 8)) {
        int k4 = k + 4;
        loadB(W1c, so + (k4 >= 12), k4 >= 12 ? k4 - 12 : k4, g[k & 3]);
      }
      if (!last) ldsbar();
    }
  }

  // ---------------- layer 2 + fused layer 3: 8 n-tiles x 8 K-steps --------
  float s0[4] = {0.f, 0.f, 0.f, 0.f}, s1[4] = {0.f, 0.f, 0.f, 0.f};
  loadB(W2c, 0, 0, g[0]);
  loadB(W2c, 0, 1, g[1]);
  loadB(W2c, 0, 2, g[2]);
  loadB(W2c, 0, 3, g[3]);
  writeB(g[0], 0);
  ldsbar();  // also publishes last h1 writes

#pragma unroll 1
  for (int so = 0; so < 8; ++so) {
#pragma unroll
    for (int k = 0; k < 8; ++k) {
      comp2(k & 1, k);
      if (k == 7) {  // epilogue: bias+relu -> W3 dot accumulate, acc reset
        const int n0 = so * 64;
#pragma unroll
        for (int nf = 0; nf < 4; nf++) {
          float bv = ((const float*)(smem + 18432))[n0 + nf * 16 + lr];
          f32x2 w3p = ((const f32x2*)(smem + 20480))[n0 + nf * 16 + lr];
#pragma unroll
          for (int r = 0; r < 4; r++) {
            float v = fmaxf(acc[nf][r] + bv, 0.f);
            s0[r] += v * w3p[0];
            s1[r] += v * w3p[1];
          }
          acc[nf] = {0.f, 0.f, 0.f, 0.f};
        }
      }
      const bool last = (so == 7 && k == 7);
      if (!last) writeB(g[(k + 1) & 3], (k + 1) & 1);
      if (!(so == 7 && k >= 4)) {
        int k4 = k + 4;
        loadB(W2c, so + (k4 >= 8 ? 1 : 0), k4 & 7, g[k & 3]);
      }
      if (!last) ldsbar();
    }
  }

  // ---------------- final: shfl-reduce over 16 lanes, store out -----------
  f32x2 b3v = *(const f32x2*)(smem + 24576);
#pragma unroll
  for (int r = 0; r < 4; r++) {
#pragma unroll
    for (int d = 1; d < 16; d <<= 1) {
      s0[r] += __shfl_xor(s0[r], d);
      s1[r] += __shfl_xor(s1[r], d);
    }
    if (lr == 0) {
      int row = mh * 128 + w * 16 + lg * 4 + r;
      *(f32x2*)(out + ((size_t)row * 512 + c) * 2) =
          f32x2{s0[r] + b3v[0], s1[r] + b3v[1]};
    }
  }
}

extern "C" void kernel_launch(void* const* d_in, const int* in_sizes, int n_in,
                              void* d_out, int out_size, void* d_ws,
                              size_t ws_size, hipStream_t stream) {
  const float* x = (const float*)d_in[0];
  const float* W1 = (const float*)d_in[1];
  const float* b1 = (const float*)d_in[2];
  const float* W2 = (const float*)d_in[3];
  const float* b2 = (const float*)d_in[4];
  const float* W3 = (const float*)d_in[5];
  const float* b3 = (const float*)d_in[6];
  float* out = (float*)d_out;

  uint8_t* ws = (uint8_t*)d_ws;
  if (ws_size < 393216) return;
  uint32_t* xb = (uint32_t*)ws;

  cast_x_kernel<<<dim3(384), dim3(256), 0, stream>>>(x, xb, 98304);
  fused_mlp<<<dim3(1024), dim3(512), 0, stream>>>(
      (const uint16_t*)xb, W1, b1, W2, b2, W3, b3, out);
}